// Round 9
// baseline (1991.091 us; speedup 1.0000x reference)
//
#include <hip/hip_runtime.h>
#include <hip/hip_cooperative_groups.h>
#include <math.h>

namespace cg = cooperative_groups;

#define TT 10
#define BB 32
#define CIN 3
#define COUT 64
#define HH 64
#define WW 64
#define HW (HH*WW)           // 4096
#define DECAY 0.2f
#define INH 1.625f
#define NSHAD 16             // shadow atomicMax slots per t (64 blocks/slot)

__device__ __forceinline__ unsigned int enc_f(float f) {
    unsigned int u = __float_as_uint(f);
    return (u & 0x80000000u) ? ~u : (u | 0x80000000u);
}
__device__ __forceinline__ float dec_f(unsigned int u) {
    u = (u & 0x80000000u) ? (u & 0x7FFFFFFFu) : ~u;
    return __uint_as_float(u);
}

// ---------------------------------------------------------------------------
// Single cooperative kernel: conv computed ONCE per (t,b,h,w,c).
// 1024 blocks x 256 threads, all co-resident (4 blocks/CU: LDS 36.3KB,
// VGPR capped 128 via __launch_bounds__(256,4) — state ~100, no spill).
// Block = (b, 2 rows); wave = half row (32 px), lane = channel; mem[32] in
// registers across all t. Per t:
//   stage x rows h0-1..h0+2 -> barrier -> conv (i into LDS [j][tid],
//   2-way-free banks) with the out zero-fill interleaved one float4/chunk
//   -> per-channel block max -> atomicMax into shadow[blockIdx&15]
//   -> grid.sync() (release: drains fill stores, publishes atomics)
//   -> combine 16 shadows (same max set => bit-identical thr) -> LIF from
//   LDS -> sparse winner stores (addresses unique; fill of same t ordered
//   before by the grid-sync fence).
// FMA order per accumulator identical to all prior rounds -> bit-identical.
// ---------------------------------------------------------------------------
__global__ __launch_bounds__(256, 4) void snn_coop(
    const float* __restrict__ x,        // (T,B,3,64,64)
    const float* __restrict__ Wt,       // (64,3,3,3)
    unsigned int* __restrict__ thrS,    // (T,16,64) pre-zeroed shadow maxes
    float* __restrict__ out)            // (T,B,64,64,64) filled here
{
    __shared__ float i_lds[32][256];    // [px j][tid]  (32 KB)
    __shared__ float sx[CIN][4][68];    // rows h0-1..h0+2, 16B-aligned rows
    __shared__ float wmax[4][COUT];

    const int tid  = threadIdx.x;
    const int lane = tid & 63;          // channel
    const int wave = tid >> 6;
    const int b    = blockIdx.x >> 5;        // 32 blocks per batch
    const int h0   = (blockIdx.x & 31) << 1; // 2 rows per block
    const int hr   = wave >> 1;              // row within pair
    const int wb   = (wave & 1) << 5;        // px base within row
    const int slot = blockIdx.x & (NSHAD - 1);

    float w[27];
    #pragma unroll
    for (int k = 0; k < 27; k++) w[k] = Wt[lane * 27 + k];

    float mem[32];
    #pragma unroll
    for (int j = 0; j < 32; j++) mem[j] = 0.f;

    cg::grid_group grid = cg::this_grid();

    const float* xb = x + (size_t)b * (CIN * HW);

    #pragma unroll 1
    for (int t = 0; t < TT; t++) {
        // ---- stage x rows h0-1..h0+2 (3ci x 4r x 66c), zero-padded ----
        for (int l = tid; l < CIN * 4 * 66; l += 256) {
            int ci  = l / 264;
            int r   = (l % 264) / 66;
            int col = l % 66;
            int gh = h0 + r - 1;
            int gw = col - 1;
            float v = 0.f;
            if (gh >= 0 && gh < HH && gw >= 0 && gw < WW)
                v = xb[(size_t)t * ((size_t)BB * CIN * HW) + ci * HW + gh * WW + gw];
            sx[ci][r][col] = v;
        }
        __syncthreads();

        float* ofill = out + ((size_t)t * BB + b) * ((size_t)COUT * HW);
        float mx = -INFINITY;

        #pragma unroll
        for (int cc = 0; cc < 8; cc++) {       // 4-px chunks (32 px / wave)
            // interleaved zero-fill: 2048 float4/block-t, 1 per thread/chunk;
            // 16 lanes cover a 256B segment -> fully coalesced
            {
                int l   = cc * 256 + tid;      // 0..2047
                int row = l >> 4;              // (c<<1)|hh
                int q   = l & 15;
                int c   = row >> 1;
                int hh  = row & 1;
                *(float4*)(ofill + (size_t)c * HW + (h0 + hh) * WW + q * 4) =
                    make_float4(0.f, 0.f, 0.f, 0.f);
            }
            const int c0 = wb + cc * 4;        // chunk px base (= sx col base)
            float acc0 = 0.f, acc1 = 0.f, acc2 = 0.f, acc3 = 0.f;
            #pragma unroll
            for (int ci = 0; ci < CIN; ci++)
                #pragma unroll
                for (int kh = 0; kh < 3; kh++) {
                    // wave-uniform LDS reads: broadcast, conflict-free
                    const float* rp = &sx[ci][hr + kh][c0];   // 16B-aligned
                    float4 q = *(const float4*)rp;
                    float2 r2 = *(const float2*)(rp + 4);
                    float x0 = q.x, x1 = q.y, x2 = q.z, x3 = q.w;
                    float x4 = r2.x, x5 = r2.y;
                    const float w0 = w[ci * 9 + kh * 3 + 0];
                    const float w1 = w[ci * 9 + kh * 3 + 1];
                    const float w2 = w[ci * 9 + kh * 3 + 2];
                    acc0 = fmaf(w0, x0, acc0); acc0 = fmaf(w1, x1, acc0); acc0 = fmaf(w2, x2, acc0);
                    acc1 = fmaf(w0, x1, acc1); acc1 = fmaf(w1, x2, acc1); acc1 = fmaf(w2, x3, acc1);
                    acc2 = fmaf(w0, x2, acc2); acc2 = fmaf(w1, x3, acc2); acc2 = fmaf(w2, x4, acc2);
                    acc3 = fmaf(w0, x3, acc3); acc3 = fmaf(w1, x4, acc3); acc3 = fmaf(w2, x5, acc3);
                }
            mx = fmaxf(mx, fmaxf(fmaxf(acc0, acc1), fmaxf(acc2, acc3)));
            // park i in LDS: column tid -> banks tid%32, 2 lanes/bank (free)
            i_lds[cc * 4 + 0][tid] = acc0;
            i_lds[cc * 4 + 1][tid] = acc1;
            i_lds[cc * 4 + 2][tid] = acc2;
            i_lds[cc * 4 + 3][tid] = acc3;
        }

        wmax[wave][lane] = mx;
        __syncthreads();
        if (wave == 0) {
            float m = fmaxf(fmaxf(wmax[0][lane], wmax[1][lane]),
                            fmaxf(wmax[2][lane], wmax[3][lane]));
            atomicMax(&thrS[(t * NSHAD + slot) * COUT + lane], enc_f(m));
        }

        grid.sync();   // publishes shadow maxes; drains this t's fill stores

        // combine 16 shadows: same max set as a single global reduce ->
        // bit-identical thr (max is order-independent)
        unsigned int tm = 0;
        #pragma unroll
        for (int s = 0; s < NSHAD; s++) {
            unsigned int v = thrS[(t * NSHAD + s) * COUT + lane];
            tm = (v > tm) ? v : tm;
        }
        float thr   = dec_f(tm) + 1e-4f;
        float sinv  = 8.0f / thr;
        float s04   = 0.4f * thr;
        float sinh_ = INH * thr;

        unsigned int fmask = 0;   // bit j: lane's channel fired at px wb+j

        #pragma unroll
        for (int j = 0; j < 32; j++) {
            float iv  = i_lds[j][tid];
            float cur = fmaxf(iv, 0.f);
            float z   = (cur - s04) * sinv;
            float sig = 1.0f / (1.0f + expf(-z));
            float m   = mem[j] * DECAY + thr * sig;
            int   sp  = m > thr;
            float score = sp ? m : 0.f;

            unsigned long long blt = __ballot(sp);
            int fr = 0, sp_any = 0;
            if (blt) {   // wave-uniform; rare
                float bs = score;
                int   bc = lane;
                #pragma unroll
                for (int off = 32; off > 0; off >>= 1) {
                    float so = __shfl_xor(bs, off, 64);
                    int   co = __shfl_xor(bc, off, 64);
                    if (so > bs || (so == bs && co < bc)) { bs = so; bc = co; }
                }
                int spw = __shfl(sp, bc, 64);   // winner's spike = any_sp
                fr     = (lane == bc) && sp;
                sp_any = spw;
            }
            mem[j] = fr ? 0.f : (m - (sp_any ? sinh_ : 0.f));
            if (fr) fmask |= (1u << j);
        }

        // sparse winner stores; fill of this t ordered before via grid.sync
        if (fmask) {
            float* os = out + ((size_t)t * BB + b) * ((size_t)COUT * HW)
                      + (h0 + hr) * WW + wb;
            #pragma unroll
            for (int j = 0; j < 32; j++)
                if (fmask & (1u << j))
                    os[(size_t)lane * HW + j] = 1.0f;
        }
        // next t's sx overwrite is safe: all conv reads of sx completed
        // before the wmax barrier; LIF touches only i_lds[.][tid] (own col).
    }
}

// ---------------------------------------------------------------------------
// Fallback path (round-8 proven kernels) in case cooperative launch is
// unavailable: conv-for-threshold + interleaved fill, then fused conv+LIF.
// ---------------------------------------------------------------------------
__global__ __launch_bounds__(256) void thr_kernel(
    const float* __restrict__ x, const float* __restrict__ Wt,
    unsigned int* __restrict__ thr_raw, float* __restrict__ out)
{
    __shared__ float sx[CIN][6][68];
    __shared__ float wmax[4][COUT];
    const int tid  = threadIdx.x;
    const int lane = tid & 63;
    const int wave = tid >> 6;
    const int h0   = blockIdx.x * 4;
    const int b    = blockIdx.y;
    const int t    = blockIdx.z;
    float w[27];
    #pragma unroll
    for (int k = 0; k < 27; k++) w[k] = Wt[lane * 27 + k];
    const float* xb = x + ((size_t)t * BB + b) * (CIN * HW);
    for (int l = tid; l < CIN * 6 * 66; l += 256) {
        int ci = l / 396, r = (l % 396) / 66, col = l % 66;
        int gh = h0 + r - 1, gw = col - 1;
        float v = 0.f;
        if (gh >= 0 && gh < HH && gw >= 0 && gw < WW) v = xb[ci * HW + gh * WW + gw];
        sx[ci][r][col] = v;
    }
    __syncthreads();
    float* ob = out + (((size_t)t * BB + b) * COUT) * HW;
    float mx = -INFINITY;
    for (int cc = 0; cc < 16; cc++) {
        { int l = cc * 256 + tid, row = l >> 4, q = l & 15, c = row >> 2, hrr = row & 3;
          *(float4*)(ob + (size_t)c * HW + (h0 + hrr) * WW + q * 4) = make_float4(0.f,0.f,0.f,0.f); }
        float acc0 = 0.f, acc1 = 0.f, acc2 = 0.f, acc3 = 0.f;
        #pragma unroll
        for (int ci = 0; ci < CIN; ci++)
            #pragma unroll
            for (int kh = 0; kh < 3; kh++) {
                const float* rp = &sx[ci][wave + kh][cc * 4];
                float4 q = *(const float4*)rp; float2 r2 = *(const float2*)(rp + 4);
                float x0=q.x,x1=q.y,x2=q.z,x3=q.w,x4=r2.x,x5=r2.y;
                const float w0=w[ci*9+kh*3+0], w1=w[ci*9+kh*3+1], w2=w[ci*9+kh*3+2];
                acc0=fmaf(w0,x0,acc0);acc0=fmaf(w1,x1,acc0);acc0=fmaf(w2,x2,acc0);
                acc1=fmaf(w0,x1,acc1);acc1=fmaf(w1,x2,acc1);acc1=fmaf(w2,x3,acc1);
                acc2=fmaf(w0,x2,acc2);acc2=fmaf(w1,x3,acc2);acc2=fmaf(w2,x4,acc2);
                acc3=fmaf(w0,x3,acc3);acc3=fmaf(w1,x4,acc3);acc3=fmaf(w2,x5,acc3);
            }
        mx = fmaxf(mx, fmaxf(fmaxf(acc0, acc1), fmaxf(acc2, acc3)));
    }
    wmax[wave][lane] = mx;
    __syncthreads();
    if (wave == 0) {
        float m = fmaxf(fmaxf(wmax[0][lane], wmax[1][lane]), fmaxf(wmax[2][lane], wmax[3][lane]));
        atomicMax(&thr_raw[t * COUT + lane], enc_f(m));
    }
}

__global__ __launch_bounds__(256) void fused_kernel(
    const float* __restrict__ x, const float* __restrict__ Wt,
    const unsigned int* __restrict__ thr_raw, float* __restrict__ out)
{
    __shared__ float sx[5][CIN][3][24];
    const int tid  = threadIdx.x;
    const int lane = tid & 63;
    const int wave = tid >> 6;
    const int p0   = __builtin_amdgcn_readfirstlane(wave * 4);
    const int b    = blockIdx.x >> 8;
    const int h    = (blockIdx.x >> 2) & 63;
    const int w0   = (blockIdx.x & 3) << 4;
    float w[27];
    #pragma unroll
    for (int k = 0; k < 27; k++) w[k] = Wt[lane * 27 + k];
    const float* xb0 = x + (size_t)b * (CIN * HW);
#define STAGE5(T0) {                                                          \
        for (int l = tid; l < 5 * 162; l += 256) {                            \
            int t = l / 162, r0 = l - t * 162, ci = r0 / 54;                  \
            int r1 = r0 - ci * 54, r = r1 / 18, col = r1 - r * 18;            \
            int gh = h + r - 1, gw = w0 + col - 1;                            \
            float v = 0.f;                                                    \
            if (gh >= 0 && gh < HH && gw >= 0 && gw < WW)                     \
                v = xb0[(size_t)((T0) + t) * ((size_t)BB * CIN * HW)          \
                        + ci * HW + gh * WW + gw];                            \
            sx[t][ci][r][col] = v;                                            \
        }                                                                     \
    }
    STAGE5(0);
    float mem[4];
    #pragma unroll
    for (int j = 0; j < 4; j++) mem[j] = 0.f;
    __syncthreads();
    #pragma unroll 1
    for (int t = 0; t < TT; t++) {
        if (t == 5) { __syncthreads(); STAGE5(5); __syncthreads(); }
        const int slot = (t < 5) ? t : t - 5;
        float thr = dec_f(thr_raw[t * COUT + lane]) + 1e-4f;
        float sinv = 8.0f / thr, s04 = 0.4f * thr, sinh_ = INH * thr;
        int fmask = 0;
        float acc0 = 0.f, acc1 = 0.f, acc2 = 0.f, acc3 = 0.f;
        #pragma unroll
        for (int ci = 0; ci < CIN; ci++)
            #pragma unroll
            for (int kh = 0; kh < 3; kh++) {
                const float* rp = &sx[slot][ci][kh][p0];
                float4 q = *(const float4*)rp; float2 r2 = *(const float2*)(rp + 4);
                float x0=q.x,x1=q.y,x2=q.z,x3=q.w,x4=r2.x,x5=r2.y;
                const float w0_=w[ci*9+kh*3+0], w1_=w[ci*9+kh*3+1], w2_=w[ci*9+kh*3+2];
                acc0=fmaf(w0_,x0,acc0);acc0=fmaf(w1_,x1,acc0);acc0=fmaf(w2_,x2,acc0);
                acc1=fmaf(w0_,x1,acc1);acc1=fmaf(w1_,x2,acc1);acc1=fmaf(w2_,x3,acc1);
                acc2=fmaf(w0_,x2,acc2);acc2=fmaf(w1_,x3,acc2);acc2=fmaf(w2_,x4,acc2);
                acc3=fmaf(w0_,x3,acc3);acc3=fmaf(w1_,x4,acc3);acc3=fmaf(w2_,x5,acc3);
            }
#define LIF_PX(J, ACC) {                                                    \
        float cur = fmaxf(ACC, 0.f);                                        \
        float z   = (cur - s04) * sinv;                                     \
        float sig = 1.0f / (1.0f + expf(-z));                               \
        float m   = mem[J] * DECAY + thr * sig;                             \
        int   sp  = m > thr;                                                \
        float score = sp ? m : 0.f;                                         \
        unsigned long long blt = __ballot(sp);                              \
        int fr = 0, sp_any = 0;                                             \
        if (blt) {                                                          \
            float bs = score; int bc = lane;                                \
            _Pragma("unroll")                                               \
            for (int off = 32; off > 0; off >>= 1) {                        \
                float so = __shfl_xor(bs, off, 64);                         \
                int   co = __shfl_xor(bc, off, 64);                         \
                if (so > bs || (so == bs && co < bc)) { bs = so; bc = co; } \
            }                                                               \
            int spw = __shfl(sp, bc, 64);                                   \
            fr = (lane == bc) && sp; sp_any = spw;                          \
        }                                                                   \
        mem[J] = fr ? 0.f : (m - (sp_any ? sinh_ : 0.f));                   \
        if (fr) fmask |= (1 << (J));                                        \
    }
        LIF_PX(0, acc0); LIF_PX(1, acc1); LIF_PX(2, acc2); LIF_PX(3, acc3);
#undef LIF_PX
        if (fmask) {
            float* os = out + (((size_t)t * BB + b) * COUT) * HW + h * WW + w0;
            #pragma unroll
            for (int j = 0; j < 4; j++)
                if (fmask & (1 << j)) os[(size_t)lane * HW + p0 + j] = 1.0f;
        }
    }
#undef STAGE5
}

// ---------------------------------------------------------------------------
extern "C" void kernel_launch(void* const* d_in, const int* in_sizes, int n_in,
                              void* d_out, int out_size, void* d_ws, size_t ws_size,
                              hipStream_t stream) {
    const float* x = (const float*)d_in[0];   // (T,B,3,64,64)
    const float* W = (const float*)d_in[1];   // (64,3,3,3)
    float* out     = (float*)d_out;           // (T,B,64,64,64)

    unsigned int* thrS = (unsigned int*)d_ws; // (T,16,64) shadow slots, 40KB
    hipMemsetAsync(thrS, 0, TT * NSHAD * COUT * sizeof(unsigned int), stream);

    void* args[] = { (void*)&x, (void*)&W, (void*)&thrS, (void*)&out };
    hipError_t err = hipLaunchCooperativeKernel(
        (const void*)snn_coop, dim3(BB * (HH / 2)), dim3(256), args, 0, stream);

    if (err != hipSuccess) {
        // fallback: round-8 two-kernel path (thr slots 0..639 reused)
        thr_kernel<<<dim3(HH / 4, BB, TT), 256, 0, stream>>>(x, W, thrS, out);
        fused_kernel<<<dim3(BB * HH * 4), 256, 0, stream>>>(x, W, thrS, out);
    }
}

// Round 10
// 523.387 us; speedup vs baseline: 3.8042x; 3.8042x over previous
//
#include <hip/hip_runtime.h>
#include <math.h>

#define TT 10
#define BB 32
#define CIN 3
#define COUT 64
#define HH 64
#define WW 64
#define HW (HH*WW)           // 4096
#define DECAY 0.2f
#define INH 1.625f

__device__ __forceinline__ unsigned int enc_f(float f) {
    unsigned int u = __float_as_uint(f);
    return (u & 0x80000000u) ? ~u : (u | 0x80000000u);
}
__device__ __forceinline__ float dec_f(unsigned int u) {
    u = (u & 0x80000000u) ? (u & 0x7FFFFFFFu) : ~u;
    return __uint_as_float(u);
}

// ---------------------------------------------------------------------------
// Pass 1: conv for the threshold max + interleaved zero-fill of the output.
// 8-PIXEL chunks: per (ci,kh) one 10-float row segment (2xb128 + 1xb64)
// feeds 24 FMAs -> 25% fewer LDS reads than the 4-px form (3 reads/24 FMA
// vs 2/12). FMA order per accumulator (ci,kh asc; kw 0,1,2) unchanged ->
// bitwise-identical i. lane = channel (W[27] in VGPRs), wave = row.
// Plain __launch_bounds__(256): NO min-occupancy arg (r2-r4/r9 spill lesson).
// ---------------------------------------------------------------------------
__global__ __launch_bounds__(256) void thr_kernel(
    const float* __restrict__ x,        // (T,B,3,64,64)
    const float* __restrict__ Wt,       // (64,3,3,3)
    unsigned int* __restrict__ thr_raw, // (T,64) pre-zeroed
    float* __restrict__ out)            // (T,B,64,64,64) — zero-filled here
{
    __shared__ float sx[CIN][6][68];    // row stride 68 -> 16B-aligned rows
    __shared__ float wmax[4][COUT];

    const int tid  = threadIdx.x;
    const int lane = tid & 63;          // channel
    const int wave = tid >> 6;          // row within 4-row group
    const int h0   = blockIdx.x * 4;
    const int b    = blockIdx.y;
    const int t    = blockIdx.z;

    float w[27];
    #pragma unroll
    for (int k = 0; k < 27; k++) w[k] = Wt[lane * 27 + k];

    // stage x tile (3 x 6 x 66 used cols), coalesced, zero-padded
    const float* xb = x + ((size_t)t * BB + b) * (CIN * HW);
    for (int l = tid; l < CIN * 6 * 66; l += 256) {
        int ci  = l / 396;
        int r   = (l % 396) / 66;
        int col = l % 66;
        int gh = h0 + r - 1;
        int gw = col - 1;
        float v = 0.f;
        if (gh >= 0 && gh < HH && gw >= 0 && gw < WW)
            v = xb[ci * HW + gh * WW + gw];
        sx[ci][r][col] = v;
    }
    __syncthreads();   // only LDS staging waits here

    float* ob = out + (((size_t)t * BB + b) * COUT) * HW;
    float mx = -INFINITY;

    for (int cc = 0; cc < 8; cc++) {           // 8-pixel chunks along the row
        // two interleaved fill stores per chunk (16 total = 64KB/block);
        // they drain under the conv FMAs, final barrier waits on them
        #pragma unroll
        for (int k = 0; k < 2; k++) {
            int l   = (cc * 2 + k) * 256 + tid;   // 0..4095 float4s
            int row = l >> 4;                     // (c<<2)|hr
            int q   = l & 15;
            int c   = row >> 2;
            int hr  = row & 3;
            *(float4*)(ob + (size_t)c * HW + (h0 + hr) * WW + q * 4) =
                make_float4(0.f, 0.f, 0.f, 0.f);
        }

        float acc[8];
        #pragma unroll
        for (int j = 0; j < 8; j++) acc[j] = 0.f;

        #pragma unroll
        for (int ci = 0; ci < CIN; ci++)
            #pragma unroll
            for (int kh = 0; kh < 3; kh++) {
                // wave-uniform LDS reads: broadcast, conflict-free
                const float* rp = &sx[ci][wave + kh][cc * 8];  // 32B-aligned
                float4 qa = *(const float4*)(rp + 0);
                float4 qb = *(const float4*)(rp + 4);
                float2 qc = *(const float2*)(rp + 8);
                float f0 = qa.x, f1 = qa.y, f2 = qa.z, f3 = qa.w;
                float f4 = qb.x, f5 = qb.y, f6 = qb.z, f7 = qb.w;
                float f8 = qc.x, f9 = qc.y;
                const float w0 = w[ci * 9 + kh * 3 + 0];
                const float w1 = w[ci * 9 + kh * 3 + 1];
                const float w2 = w[ci * 9 + kh * 3 + 2];
                acc[0] = fmaf(w0, f0, acc[0]); acc[0] = fmaf(w1, f1, acc[0]); acc[0] = fmaf(w2, f2, acc[0]);
                acc[1] = fmaf(w0, f1, acc[1]); acc[1] = fmaf(w1, f2, acc[1]); acc[1] = fmaf(w2, f3, acc[1]);
                acc[2] = fmaf(w0, f2, acc[2]); acc[2] = fmaf(w1, f3, acc[2]); acc[2] = fmaf(w2, f4, acc[2]);
                acc[3] = fmaf(w0, f3, acc[3]); acc[3] = fmaf(w1, f4, acc[3]); acc[3] = fmaf(w2, f5, acc[3]);
                acc[4] = fmaf(w0, f4, acc[4]); acc[4] = fmaf(w1, f5, acc[4]); acc[4] = fmaf(w2, f6, acc[4]);
                acc[5] = fmaf(w0, f5, acc[5]); acc[5] = fmaf(w1, f6, acc[5]); acc[5] = fmaf(w2, f7, acc[5]);
                acc[6] = fmaf(w0, f6, acc[6]); acc[6] = fmaf(w1, f7, acc[6]); acc[6] = fmaf(w2, f8, acc[6]);
                acc[7] = fmaf(w0, f7, acc[7]); acc[7] = fmaf(w1, f8, acc[7]); acc[7] = fmaf(w2, f9, acc[7]);
            }

        #pragma unroll
        for (int j = 0; j < 8; j++) mx = fmaxf(mx, acc[j]);
    }

    wmax[wave][lane] = mx;
    __syncthreads();   // drains the interleaved fill too (hidden under conv)
    if (wave == 0) {
        float m = fmaxf(fmaxf(wmax[0][lane], wmax[1][lane]),
                        fmaxf(wmax[2][lane], wmax[3][lane]));
        atomicMax(&thr_raw[t * COUT + lane], enc_f(m));
    }
}

// ---------------------------------------------------------------------------
// Pass 2: fused conv + LIF, HALF-ROW blocks, ALL-t staging, 8-px chunks.
// grid = B*H*2 = 4096 blocks; wave owns 8 pixels (mem[8]). All 10 t of the
// 3-row x slab staged up front ([10][3][3][36] = 12.96 KB) -> ONE barrier
// in the whole kernel, no mid-loop restage. Conv: per (ci,kh) one 10-float
// segment (2xb128+1xb64) feeds 24 FMAs (25% fewer LDS reads). FMA order
// per accumulator unchanged -> bit-identical i. out pre-zeroed by
// thr_kernel; only sparse winner stores (unique addresses, no ordering).
// Plain __launch_bounds__(256): no occupancy hint.
// ---------------------------------------------------------------------------
__global__ __launch_bounds__(256) void fused_kernel(
    const float* __restrict__ x,              // (T,B,3,64,64)
    const float* __restrict__ Wt,             // (64,3,3,3)
    const unsigned int* __restrict__ thr_raw, // (T,64)
    float* __restrict__ out)                  // (T,B,64,64,64) pre-zeroed
{
    __shared__ float sx[TT][CIN][3][36];      // 12,960 B; row stride 144B

    const int tid  = threadIdx.x;
    const int lane = tid & 63;                            // channel
    const int wave = tid >> 6;
    const int p0   = __builtin_amdgcn_readfirstlane(wave * 8);  // local px base
    const int b    = blockIdx.x >> 7;
    const int h    = (blockIdx.x >> 1) & 63;
    const int w0   = (blockIdx.x & 1) << 5;               // half-row start

    float w[27];
    #pragma unroll
    for (int k = 0; k < 27; k++) w[k] = Wt[lane * 27 + k];

    // ---- stage all 10 t: rows h-1..h+1, cols w0-1..w0+32 (34 used) ----
    {
        const float* xb0 = x + (size_t)b * (CIN * HW);
        for (int l = tid; l < TT * 306; l += 256) {       // 306 = 3*3*34
            int t   = l / 306;
            int r0  = l - t * 306;
            int ci  = r0 / 102;
            int r1  = r0 - ci * 102;
            int r   = r1 / 34;
            int col = r1 - r * 34;
            int gh = h + r - 1;
            int gw = w0 + col - 1;
            float v = 0.f;
            if (gh >= 0 && gh < HH && gw >= 0 && gw < WW)
                v = xb0[(size_t)t * ((size_t)BB * CIN * HW)
                        + ci * HW + gh * WW + gw];
            sx[t][ci][r][col] = v;
        }
    }

    float mem[8];
    #pragma unroll
    for (int j = 0; j < 8; j++) mem[j] = 0.f;

    __syncthreads();   // the only barrier in this kernel

    #pragma unroll 1
    for (int t = 0; t < TT; t++) {
        // per-lane (= per-channel) threshold constants (L2-resident 2.5 KB)
        float thr   = dec_f(thr_raw[t * COUT + lane]) + 1e-4f;
        float sinv  = 8.0f / thr;
        float s04   = 0.4f * thr;
        float sinh_ = INH * thr;

        // ---- conv: one 8-px chunk, 3 LDS reads per (ci,kh) ----
        float acc[8];
        #pragma unroll
        for (int j = 0; j < 8; j++) acc[j] = 0.f;

        #pragma unroll
        for (int ci = 0; ci < CIN; ci++)
            #pragma unroll
            for (int kh = 0; kh < 3; kh++) {
                // wave-uniform LDS reads: broadcast, conflict-free;
                // col p0 holds x[w0+p0-1] -> operand at kw=-1 of pixel p0
                const float* rp = &sx[t][ci][kh][p0];     // 32B-aligned
                float4 qa = *(const float4*)(rp + 0);
                float4 qb = *(const float4*)(rp + 4);
                float2 qc = *(const float2*)(rp + 8);
                float f0 = qa.x, f1 = qa.y, f2 = qa.z, f3 = qa.w;
                float f4 = qb.x, f5 = qb.y, f6 = qb.z, f7 = qb.w;
                float f8 = qc.x, f9 = qc.y;
                const float w0_ = w[ci * 9 + kh * 3 + 0];
                const float w1_ = w[ci * 9 + kh * 3 + 1];
                const float w2_ = w[ci * 9 + kh * 3 + 2];
                acc[0] = fmaf(w0_, f0, acc[0]); acc[0] = fmaf(w1_, f1, acc[0]); acc[0] = fmaf(w2_, f2, acc[0]);
                acc[1] = fmaf(w0_, f1, acc[1]); acc[1] = fmaf(w1_, f2, acc[1]); acc[1] = fmaf(w2_, f3, acc[1]);
                acc[2] = fmaf(w0_, f2, acc[2]); acc[2] = fmaf(w1_, f3, acc[2]); acc[2] = fmaf(w2_, f4, acc[2]);
                acc[3] = fmaf(w0_, f3, acc[3]); acc[3] = fmaf(w1_, f4, acc[3]); acc[3] = fmaf(w2_, f5, acc[3]);
                acc[4] = fmaf(w0_, f4, acc[4]); acc[4] = fmaf(w1_, f5, acc[4]); acc[4] = fmaf(w2_, f6, acc[4]);
                acc[5] = fmaf(w0_, f5, acc[5]); acc[5] = fmaf(w1_, f6, acc[5]); acc[5] = fmaf(w2_, f7, acc[5]);
                acc[6] = fmaf(w0_, f6, acc[6]); acc[6] = fmaf(w1_, f7, acc[6]); acc[6] = fmaf(w2_, f8, acc[6]);
                acc[7] = fmaf(w0_, f7, acc[7]); acc[7] = fmaf(w1_, f8, acc[7]); acc[7] = fmaf(w2_, f9, acc[7]);
            }

        int fmask = 0;     // bit j: this lane's channel fired at px p0+j

#define LIF_PX(J) {                                                         \
        float cur = fmaxf(acc[J], 0.f);                                     \
        float z   = (cur - s04) * sinv;                                     \
        float sig = 1.0f / (1.0f + expf(-z));                               \
        float m   = mem[J] * DECAY + thr * sig;                             \
        int   sp  = m > thr;                                                \
        float score = sp ? m : 0.f;                                         \
        unsigned long long blt = __ballot(sp);                              \
        int fr = 0, sp_any = 0;                                             \
        if (blt) {   /* wave-uniform; rare */                               \
            float bs = score;                                               \
            int   bc = lane;                                                \
            _Pragma("unroll")                                               \
            for (int off = 32; off > 0; off >>= 1) {                        \
                float so = __shfl_xor(bs, off, 64);                         \
                int   co = __shfl_xor(bc, off, 64);                         \
                if (so > bs || (so == bs && co < bc)) { bs = so; bc = co; } \
            }                                                               \
            int spw = __shfl(sp, bc, 64);   /* winner's spike = any_sp */   \
            fr     = (lane == bc) && sp;                                    \
            sp_any = spw;                                                   \
        }                                                                   \
        mem[J] = fr ? 0.f : (m - (sp_any ? sinh_ : 0.f));                   \
        if (fr) fmask |= (1 << (J));                                        \
    }

        LIF_PX(0); LIF_PX(1); LIF_PX(2); LIF_PX(3);
        LIF_PX(4); LIF_PX(5); LIF_PX(6); LIF_PX(7);
#undef LIF_PX

        // sparse winner stores (rare); out pre-zeroed by thr_kernel; each
        // address written by exactly one thread -> no ordering needed
        if (fmask) {
            float* os = out + (((size_t)t * BB + b) * COUT) * HW + h * WW + w0;
            #pragma unroll
            for (int j = 0; j < 8; j++)
                if (fmask & (1 << j))
                    os[(size_t)lane * HW + p0 + j] = 1.0f;
        }
    }
}

// ---------------------------------------------------------------------------
extern "C" void kernel_launch(void* const* d_in, const int* in_sizes, int n_in,
                              void* d_out, int out_size, void* d_ws, size_t ws_size,
                              hipStream_t stream) {
    const float* x = (const float*)d_in[0];   // (T,B,3,64,64)
    const float* W = (const float*)d_in[1];   // (64,3,3,3)
    float* out     = (float*)d_out;           // (T,B,64,64,64)

    unsigned int* thr = (unsigned int*)d_ws;  // (T,64) — only 2.5 KB of ws used
    hipMemsetAsync(thr, 0, TT * COUT * sizeof(unsigned int), stream);

    thr_kernel<<<dim3(HH / 4, BB, TT), 256, 0, stream>>>(x, W, thr, out);
    fused_kernel<<<dim3(BB * HH * 2), 256, 0, stream>>>(x, W, thr, out);
}

// Round 11
// 494.096 us; speedup vs baseline: 4.0298x; 1.0593x over previous
//
#include <hip/hip_runtime.h>
#include <math.h>

#define TT 10
#define BB 32
#define CIN 3
#define COUT 64
#define HH 64
#define WW 64
#define HW (HH*WW)           // 4096
#define DECAY 0.2f
#define INH 1.625f

typedef __attribute__((ext_vector_type(2))) float f32x2;

__device__ __forceinline__ unsigned int enc_f(float f) {
    unsigned int u = __float_as_uint(f);
    return (u & 0x80000000u) ? ~u : (u | 0x80000000u);
}
__device__ __forceinline__ float dec_f(unsigned int u) {
    u = (u & 0x80000000u) ? (u & 0x7FFFFFFFu) : ~u;
    return __uint_as_float(u);
}

// Packed f32 FMA, broadcasting one half of the weight pair to both lanes.
// v_pk_fma_f32 is IEEE fma per 32b lane -> bit-identical to scalar fmaf.
// acc.{x,y} += w2.lo * x2.{x,y}
__device__ __forceinline__ void pkfma_lo(f32x2& acc, f32x2 w2, f32x2 x2) {
    asm("v_pk_fma_f32 %0, %1, %2, %0 op_sel:[0,0,0] op_sel_hi:[0,1,1]"
        : "+v"(acc) : "v"(w2), "v"(x2));
}
// acc.{x,y} += w2.hi * x2.{x,y}
__device__ __forceinline__ void pkfma_hi(f32x2& acc, f32x2 w2, f32x2 x2) {
    asm("v_pk_fma_f32 %0, %1, %2, %0 op_sel:[1,0,0] op_sel_hi:[1,1,1]"
        : "+v"(acc) : "v"(w2), "v"(x2));
}
// FI is compile-time after unrolling -> branch folds away
#define CONV_TAP(ACC, FI, X2) { if ((FI) & 1) pkfma_hi(ACC, wp[(FI)>>1], X2); \
                                else          pkfma_lo(ACC, wp[(FI)>>1], X2); }

// One (ci,kh) slice: 10 aligned f32x2 LDS reads feed 24 pk_fma (= 48 FMAs
// covering 8 pixels x 3 taps x 2 timesteps). Per-acc tap order w0,w1,w2
// with (ci,kh) ascending == all prior rounds -> bit-identical i.
#define CKH(RP, FB)                                                           \
    {                                                                         \
        const f32x2* rp_ = (RP);                                              \
        f32x2 d0 = rp_[0], d1 = rp_[1], d2 = rp_[2], d3 = rp_[3],             \
              d4 = rp_[4], d5 = rp_[5], d6 = rp_[6], d7 = rp_[7],             \
              d8 = rp_[8], d9 = rp_[9];                                       \
        CONV_TAP(a0, (FB)+0, d0); CONV_TAP(a0, (FB)+1, d1); CONV_TAP(a0, (FB)+2, d2); \
        CONV_TAP(a1, (FB)+0, d1); CONV_TAP(a1, (FB)+1, d2); CONV_TAP(a1, (FB)+2, d3); \
        CONV_TAP(a2, (FB)+0, d2); CONV_TAP(a2, (FB)+1, d3); CONV_TAP(a2, (FB)+2, d4); \
        CONV_TAP(a3, (FB)+0, d3); CONV_TAP(a3, (FB)+1, d4); CONV_TAP(a3, (FB)+2, d5); \
        CONV_TAP(a4, (FB)+0, d4); CONV_TAP(a4, (FB)+1, d5); CONV_TAP(a4, (FB)+2, d6); \
        CONV_TAP(a5, (FB)+0, d5); CONV_TAP(a5, (FB)+1, d6); CONV_TAP(a5, (FB)+2, d7); \
        CONV_TAP(a6, (FB)+0, d6); CONV_TAP(a6, (FB)+1, d7); CONV_TAP(a6, (FB)+2, d8); \
        CONV_TAP(a7, (FB)+0, d7); CONV_TAP(a7, (FB)+1, d8); CONV_TAP(a7, (FB)+2, d9); \
    }

#define LOAD_WP                                                               \
    f32x2 wp[14];                                                             \
    {                                                                         \
        const float* wl = Wt + lane * 27;                                     \
        _Pragma("unroll")                                                     \
        for (int k = 0; k < 13; k++) { f32x2 t_; t_.x = wl[2*k]; t_.y = wl[2*k+1]; wp[k] = t_; } \
        { f32x2 t_; t_.x = wl[26]; t_.y = wl[26]; wp[13] = t_; }              \
    }

// ---------------------------------------------------------------------------
// Pass 1: threshold max + interleaved zero-fill, TWO timesteps per block
// (t-pair packed conv via v_pk_fma_f32: 2 FMAs/instr, bit-exact).
// Grid (16 rowgroups, B, 5 t-pairs) x 256; wave = row, lane = channel.
// Plain __launch_bounds__(256): no occupancy hint (r2-r4/r9 spill lesson).
// ---------------------------------------------------------------------------
__global__ __launch_bounds__(256) void thr_kernel(
    const float* __restrict__ x,        // (T,B,3,64,64)
    const float* __restrict__ Wt,       // (64,3,3,3)
    unsigned int* __restrict__ thr_raw, // (T,64) pre-zeroed
    float* __restrict__ out)            // (T,B,64,64,64) — zero-filled here
{
    __shared__ f32x2 sx[CIN][6][68];    // t-pair interleaved, 9.8 KB
    __shared__ float wmax[4][2][COUT];

    const int tid  = threadIdx.x;
    const int lane = tid & 63;          // channel
    const int wave = tid >> 6;          // row within 4-row group
    const int h0   = blockIdx.x * 4;
    const int b    = blockIdx.y;
    const int t0   = blockIdx.z * 2;    // even timestep of the pair

    LOAD_WP

    // stage x tile for BOTH t (3ci x 6r x 66c pairs), coalesced, zero-padded
    const float* xb0 = x + ((size_t)t0 * BB + b) * (CIN * HW);
    const float* xb1 = xb0 + (size_t)BB * CIN * HW;
    for (int l = tid; l < CIN * 6 * 66; l += 256) {
        int ci  = l / 396;
        int r   = (l % 396) / 66;
        int col = l % 66;
        int gh = h0 + r - 1;
        int gw = col - 1;
        f32x2 v; v.x = 0.f; v.y = 0.f;
        if (gh >= 0 && gh < HH && gw >= 0 && gw < WW) {
            size_t off = (size_t)ci * HW + gh * WW + gw;
            v.x = xb0[off];
            v.y = xb1[off];
        }
        sx[ci][r][col] = v;
    }
    __syncthreads();   // only LDS staging waits here

    float mx0 = -INFINITY, mx1 = -INFINITY;

    for (int cc = 0; cc < 8; cc++) {           // 8-pixel chunks along the row
        // interleaved zero-fill: 4 float4/thread/chunk (2 t-slabs = 128KB)
        #pragma unroll
        for (int k = 0; k < 4; k++) {
            int l   = cc * 1024 + k * 256 + tid;   // 0..8191 float4s
            int th  = l >> 12;                     // which t of the pair
            int row = (l >> 4) & 255;              // (c<<2)|hr
            int q   = l & 15;
            int c   = row >> 2;
            int hr  = row & 3;
            float* ob = out + (((size_t)(t0 + th) * BB + b) * COUT) * HW;
            *(float4*)(ob + (size_t)c * HW + (h0 + hr) * WW + q * 4) =
                make_float4(0.f, 0.f, 0.f, 0.f);
        }

        f32x2 a0={0.f,0.f},a1={0.f,0.f},a2={0.f,0.f},a3={0.f,0.f},
              a4={0.f,0.f},a5={0.f,0.f},a6={0.f,0.f},a7={0.f,0.f};
        #pragma unroll
        for (int ci = 0; ci < CIN; ci++)
            #pragma unroll
            for (int kh = 0; kh < 3; kh++)
                CKH(&sx[ci][wave + kh][cc * 8], ci * 9 + kh * 3);

        // max is order-independent -> tree form is bit-identical
        mx0 = fmaxf(mx0, fmaxf(fmaxf(fmaxf(a0.x,a1.x),fmaxf(a2.x,a3.x)),
                               fmaxf(fmaxf(a4.x,a5.x),fmaxf(a6.x,a7.x))));
        mx1 = fmaxf(mx1, fmaxf(fmaxf(fmaxf(a0.y,a1.y),fmaxf(a2.y,a3.y)),
                               fmaxf(fmaxf(a4.y,a5.y),fmaxf(a6.y,a7.y))));
    }

    wmax[wave][0][lane] = mx0;
    wmax[wave][1][lane] = mx1;
    __syncthreads();   // drains the interleaved fill too (hidden under conv)
    if (wave < 2) {    // wave 0 reduces t0, wave 1 reduces t1 (parallel)
        float m = fmaxf(fmaxf(wmax[0][wave][lane], wmax[1][wave][lane]),
                        fmaxf(wmax[2][wave][lane], wmax[3][wave][lane]));
        atomicMax(&thr_raw[(t0 + wave) * COUT + lane], enc_f(m));
    }
}

// ---------------------------------------------------------------------------
// Pass 2: fused conv + LIF, half-row blocks, t-pair packed conv.
// Grid = B*H*2 = 4096 x 256; wave owns 8 pixels (mem[8] across all t).
// All 5 t-pairs staged up front (13 KB, t-interleaved f32x2) -> ONE barrier.
// Conv produces (i_t0, i_t1) pairs; LIF runs t0 then t1 (recurrence order
// preserved). out pre-zeroed by thr_kernel; only sparse winner stores.
// ---------------------------------------------------------------------------
__global__ __launch_bounds__(256) void fused_kernel(
    const float* __restrict__ x,              // (T,B,3,64,64)
    const float* __restrict__ Wt,             // (64,3,3,3)
    const unsigned int* __restrict__ thr_raw, // (T,64)
    float* __restrict__ out)                  // (T,B,64,64,64) pre-zeroed
{
    __shared__ f32x2 sx[5][CIN][3][36];       // 12,960 B, t-pair interleaved

    const int tid  = threadIdx.x;
    const int lane = tid & 63;                            // channel
    const int wave = tid >> 6;
    const int p0   = __builtin_amdgcn_readfirstlane(wave * 8);  // local px base
    const int b    = blockIdx.x >> 7;
    const int h    = (blockIdx.x >> 1) & 63;
    const int w0   = (blockIdx.x & 1) << 5;               // half-row start

    LOAD_WP

    // ---- stage all 5 t-pairs: rows h-1..h+1, cols w0-1..w0+32 ----
    {
        const float* xb0 = x + (size_t)b * (CIN * HW);
        const size_t ts = (size_t)BB * CIN * HW;
        for (int l = tid; l < 5 * 306; l += 256) {        // 306 = 3*3*34
            int tp  = l / 306;
            int r0  = l - tp * 306;
            int ci  = r0 / 102;
            int r1  = r0 - ci * 102;
            int r   = r1 / 34;
            int col = r1 - r * 34;
            int gh = h + r - 1;
            int gw = w0 + col - 1;
            f32x2 v; v.x = 0.f; v.y = 0.f;
            if (gh >= 0 && gh < HH && gw >= 0 && gw < WW) {
                size_t off = (size_t)ci * HW + gh * WW + gw;
                v.x = xb0[(size_t)(2 * tp)     * ts + off];
                v.y = xb0[(size_t)(2 * tp + 1) * ts + off];
            }
            sx[tp][ci][r][col] = v;
        }
    }

    float mem[8];
    #pragma unroll
    for (int j = 0; j < 8; j++) mem[j] = 0.f;

    __syncthreads();   // the only barrier in this kernel

#define LIF_PX(J, V) {                                                      \
        float cur = fmaxf(V, 0.f);                                          \
        float z   = (cur - s04) * sinv;                                     \
        float sig = 1.0f / (1.0f + expf(-z));                               \
        float m   = mem[J] * DECAY + thr * sig;                             \
        int   sp  = m > thr;                                                \
        float score = sp ? m : 0.f;                                         \
        unsigned long long blt = __ballot(sp);                              \
        int fr = 0, sp_any = 0;                                             \
        if (blt) {   /* wave-uniform; rare */                               \
            float bs = score;                                               \
            int   bc = lane;                                                \
            _Pragma("unroll")                                               \
            for (int off = 32; off > 0; off >>= 1) {                        \
                float so = __shfl_xor(bs, off, 64);                         \
                int   co = __shfl_xor(bc, off, 64);                         \
                if (so > bs || (so == bs && co < bc)) { bs = so; bc = co; } \
            }                                                               \
            int spw = __shfl(sp, bc, 64);   /* winner's spike = any_sp */   \
            fr     = (lane == bc) && sp;                                    \
            sp_any = spw;                                                   \
        }                                                                   \
        mem[J] = fr ? 0.f : (m - (sp_any ? sinh_ : 0.f));                   \
        if (fr) fmask |= (1 << (J));                                        \
    }

    #pragma unroll 1
    for (int tp = 0; tp < 5; tp++) {
        // both thresholds loaded early (latency hides under conv)
        unsigned int tru0 = thr_raw[(2 * tp)     * COUT + lane];
        unsigned int tru1 = thr_raw[(2 * tp + 1) * COUT + lane];

        f32x2 a0={0.f,0.f},a1={0.f,0.f},a2={0.f,0.f},a3={0.f,0.f},
              a4={0.f,0.f},a5={0.f,0.f},a6={0.f,0.f},a7={0.f,0.f};
        #pragma unroll
        for (int ci = 0; ci < CIN; ci++)
            #pragma unroll
            for (int kh = 0; kh < 3; kh++)
                CKH(&sx[tp][ci][kh][p0], ci * 9 + kh * 3);

        // ---- LIF t = 2*tp (lane .x) ----
        {
            float thr   = dec_f(tru0) + 1e-4f;
            float sinv  = 8.0f / thr;
            float s04   = 0.4f * thr;
            float sinh_ = INH * thr;
            int fmask = 0;
            LIF_PX(0, a0.x); LIF_PX(1, a1.x); LIF_PX(2, a2.x); LIF_PX(3, a3.x);
            LIF_PX(4, a4.x); LIF_PX(5, a5.x); LIF_PX(6, a6.x); LIF_PX(7, a7.x);
            if (fmask) {
                float* os = out + (((size_t)(2 * tp) * BB + b) * COUT) * HW
                          + h * WW + w0;
                #pragma unroll
                for (int j = 0; j < 8; j++)
                    if (fmask & (1 << j))
                        os[(size_t)lane * HW + p0 + j] = 1.0f;
            }
        }
        // ---- LIF t = 2*tp+1 (lane .y) ----
        {
            float thr   = dec_f(tru1) + 1e-4f;
            float sinv  = 8.0f / thr;
            float s04   = 0.4f * thr;
            float sinh_ = INH * thr;
            int fmask = 0;
            LIF_PX(0, a0.y); LIF_PX(1, a1.y); LIF_PX(2, a2.y); LIF_PX(3, a3.y);
            LIF_PX(4, a4.y); LIF_PX(5, a5.y); LIF_PX(6, a6.y); LIF_PX(7, a7.y);
            if (fmask) {
                float* os = out + (((size_t)(2 * tp + 1) * BB + b) * COUT) * HW
                          + h * WW + w0;
                #pragma unroll
                for (int j = 0; j < 8; j++)
                    if (fmask & (1 << j))
                        os[(size_t)lane * HW + p0 + j] = 1.0f;
            }
        }
    }
#undef LIF_PX
}

// ---------------------------------------------------------------------------
extern "C" void kernel_launch(void* const* d_in, const int* in_sizes, int n_in,
                              void* d_out, int out_size, void* d_ws, size_t ws_size,
                              hipStream_t stream) {
    const float* x = (const float*)d_in[0];   // (T,B,3,64,64)
    const float* W = (const float*)d_in[1];   // (64,3,3,3)
    float* out     = (float*)d_out;           // (T,B,64,64,64)

    unsigned int* thr = (unsigned int*)d_ws;  // (T,64) — only 2.5 KB of ws used
    hipMemsetAsync(thr, 0, TT * COUT * sizeof(unsigned int), stream);

    thr_kernel<<<dim3(HH / 4, BB, TT / 2), 256, 0, stream>>>(x, W, thr, out);
    fused_kernel<<<dim3(BB * HH * 2), 256, 0, stream>>>(x, W, thr, out);
}

// Round 12
// 493.454 us; speedup vs baseline: 4.0350x; 1.0013x over previous
//
#include <hip/hip_runtime.h>
#include <math.h>

#define TT 10
#define BB 32
#define CIN 3
#define COUT 64
#define HH 64
#define WW 64
#define HW (HH*WW)           // 4096
#define DECAY 0.2f
#define INH 1.625f

typedef __attribute__((ext_vector_type(2))) float f32x2;

__device__ __forceinline__ unsigned int enc_f(float f) {
    unsigned int u = __float_as_uint(f);
    return (u & 0x80000000u) ? ~u : (u | 0x80000000u);
}
__device__ __forceinline__ float dec_f(unsigned int u) {
    u = (u & 0x80000000u) ? (u & 0x7FFFFFFFu) : ~u;
    return __uint_as_float(u);
}

// Packed f32 FMA, broadcasting one half of the weight pair to both lanes.
// v_pk_fma_f32 is IEEE fma per 32b lane -> bit-identical to scalar fmaf.
__device__ __forceinline__ void pkfma_lo(f32x2& acc, f32x2 w2, f32x2 x2) {
    asm("v_pk_fma_f32 %0, %1, %2, %0 op_sel:[0,0,0] op_sel_hi:[0,1,1]"
        : "+v"(acc) : "v"(w2), "v"(x2));
}
__device__ __forceinline__ void pkfma_hi(f32x2& acc, f32x2 w2, f32x2 x2) {
    asm("v_pk_fma_f32 %0, %1, %2, %0 op_sel:[1,0,0] op_sel_hi:[1,1,1]"
        : "+v"(acc) : "v"(w2), "v"(x2));
}
#define CONV_TAP(ACC, FI, X2) { if ((FI) & 1) pkfma_hi(ACC, wp[(FI)>>1], X2); \
                                else          pkfma_lo(ACC, wp[(FI)>>1], X2); }

// One (ci,kh) slice: FIVE ds_read_b128 (was ten b64 — broadcast reads are
// mostly per-instruction cost on the CU-shared LDS pipe, so wider = fewer
// issue slots) feed 24 pk_fma (= 48 FMAs: 8 px x 3 taps x 2 timesteps).
// d-values and per-acc tap order (w0,w1,w2; ci,kh ascending) identical to
// r11 -> bit-identical i.
#define CKH(RP, FB)                                                           \
    {                                                                         \
        const float* rpf_ = (const float*)(RP);                              \
        float4 q0_ = *(const float4*)(rpf_ + 0);                              \
        float4 q1_ = *(const float4*)(rpf_ + 4);                              \
        float4 q2_ = *(const float4*)(rpf_ + 8);                              \
        float4 q3_ = *(const float4*)(rpf_ + 12);                             \
        float4 q4_ = *(const float4*)(rpf_ + 16);                             \
        f32x2 d0 = {q0_.x, q0_.y}, d1 = {q0_.z, q0_.w},                       \
              d2 = {q1_.x, q1_.y}, d3 = {q1_.z, q1_.w},                       \
              d4 = {q2_.x, q2_.y}, d5 = {q2_.z, q2_.w},                       \
              d6 = {q3_.x, q3_.y}, d7 = {q3_.z, q3_.w},                       \
              d8 = {q4_.x, q4_.y}, d9 = {q4_.z, q4_.w};                       \
        CONV_TAP(a0, (FB)+0, d0); CONV_TAP(a0, (FB)+1, d1); CONV_TAP(a0, (FB)+2, d2); \
        CONV_TAP(a1, (FB)+0, d1); CONV_TAP(a1, (FB)+1, d2); CONV_TAP(a1, (FB)+2, d3); \
        CONV_TAP(a2, (FB)+0, d2); CONV_TAP(a2, (FB)+1, d3); CONV_TAP(a2, (FB)+2, d4); \
        CONV_TAP(a3, (FB)+0, d3); CONV_TAP(a3, (FB)+1, d4); CONV_TAP(a3, (FB)+2, d5); \
        CONV_TAP(a4, (FB)+0, d4); CONV_TAP(a4, (FB)+1, d5); CONV_TAP(a4, (FB)+2, d6); \
        CONV_TAP(a5, (FB)+0, d5); CONV_TAP(a5, (FB)+1, d6); CONV_TAP(a5, (FB)+2, d7); \
        CONV_TAP(a6, (FB)+0, d6); CONV_TAP(a6, (FB)+1, d7); CONV_TAP(a6, (FB)+2, d8); \
        CONV_TAP(a7, (FB)+0, d7); CONV_TAP(a7, (FB)+1, d8); CONV_TAP(a7, (FB)+2, d9); \
    }

#define LOAD_WP                                                               \
    f32x2 wp[14];                                                             \
    {                                                                         \
        const float* wl = Wt + lane * 27;                                     \
        _Pragma("unroll")                                                     \
        for (int k = 0; k < 13; k++) { f32x2 t_; t_.x = wl[2*k]; t_.y = wl[2*k+1]; wp[k] = t_; } \
        { f32x2 t_; t_.x = wl[26]; t_.y = wl[26]; wp[13] = t_; }              \
    }

// ---------------------------------------------------------------------------
// Pass 1: threshold max + interleaved zero-fill, two timesteps per block
// (t-pair packed conv). Grid (16 rowgroups, B, 5 t-pairs) x 256.
// Plain __launch_bounds__(256): no occupancy hint (r2-r4/r9 spill lesson).
// Same as r11 except CKH now uses b128 broadcast reads.
// ---------------------------------------------------------------------------
__global__ __launch_bounds__(256) void thr_kernel(
    const float* __restrict__ x,        // (T,B,3,64,64)
    const float* __restrict__ Wt,       // (64,3,3,3)
    unsigned int* __restrict__ thr_raw, // (T,64) pre-zeroed
    float* __restrict__ out)            // (T,B,64,64,64) — zero-filled here
{
    __shared__ f32x2 sx[CIN][6][68];    // t-pair interleaved, 9.8 KB
    __shared__ float wmax[4][2][COUT];

    const int tid  = threadIdx.x;
    const int lane = tid & 63;          // channel
    const int wave = tid >> 6;          // row within 4-row group
    const int h0   = blockIdx.x * 4;
    const int b    = blockIdx.y;
    const int t0   = blockIdx.z * 2;    // even timestep of the pair

    LOAD_WP

    // stage x tile for BOTH t (3ci x 6r x 66c pairs), coalesced, zero-padded
    const float* xb0 = x + ((size_t)t0 * BB + b) * (CIN * HW);
    const float* xb1 = xb0 + (size_t)BB * CIN * HW;
    for (int l = tid; l < CIN * 6 * 66; l += 256) {
        int ci  = l / 396;
        int r   = (l % 396) / 66;
        int col = l % 66;
        int gh = h0 + r - 1;
        int gw = col - 1;
        f32x2 v; v.x = 0.f; v.y = 0.f;
        if (gh >= 0 && gh < HH && gw >= 0 && gw < WW) {
            size_t off = (size_t)ci * HW + gh * WW + gw;
            v.x = xb0[off];
            v.y = xb1[off];
        }
        sx[ci][r][col] = v;
    }
    __syncthreads();   // only LDS staging waits here

    float mx0 = -INFINITY, mx1 = -INFINITY;

    for (int cc = 0; cc < 8; cc++) {           // 8-pixel chunks along the row
        // interleaved zero-fill: 4 float4/thread/chunk (2 t-slabs = 128KB)
        #pragma unroll
        for (int k = 0; k < 4; k++) {
            int l   = cc * 1024 + k * 256 + tid;   // 0..8191 float4s
            int th  = l >> 12;                     // which t of the pair
            int row = (l >> 4) & 255;              // (c<<2)|hr
            int q   = l & 15;
            int c   = row >> 2;
            int hr  = row & 3;
            float* ob = out + (((size_t)(t0 + th) * BB + b) * COUT) * HW;
            *(float4*)(ob + (size_t)c * HW + (h0 + hr) * WW + q * 4) =
                make_float4(0.f, 0.f, 0.f, 0.f);
        }

        f32x2 a0={0.f,0.f},a1={0.f,0.f},a2={0.f,0.f},a3={0.f,0.f},
              a4={0.f,0.f},a5={0.f,0.f},a6={0.f,0.f},a7={0.f,0.f};
        #pragma unroll
        for (int ci = 0; ci < CIN; ci++)
            #pragma unroll
            for (int kh = 0; kh < 3; kh++)
                CKH(&sx[ci][wave + kh][cc * 8], ci * 9 + kh * 3);

        // max is order-independent -> tree form is bit-identical
        mx0 = fmaxf(mx0, fmaxf(fmaxf(fmaxf(a0.x,a1.x),fmaxf(a2.x,a3.x)),
                               fmaxf(fmaxf(a4.x,a5.x),fmaxf(a6.x,a7.x))));
        mx1 = fmaxf(mx1, fmaxf(fmaxf(fmaxf(a0.y,a1.y),fmaxf(a2.y,a3.y)),
                               fmaxf(fmaxf(a4.y,a5.y),fmaxf(a6.y,a7.y))));
    }

    wmax[wave][0][lane] = mx0;
    wmax[wave][1][lane] = mx1;
    __syncthreads();   // drains the interleaved fill too (hidden under conv)
    if (wave < 2) {    // wave 0 reduces t0, wave 1 reduces t1 (parallel)
        float m = fmaxf(fmaxf(wmax[0][wave][lane], wmax[1][wave][lane]),
                        fmaxf(wmax[2][wave][lane], wmax[3][wave][lane]));
        atomicMax(&thr_raw[(t0 + wave) * COUT + lane], enc_f(m));
    }
}

// ---------------------------------------------------------------------------
// Pass 2: fused conv + LIF, half-row blocks, t-pair packed conv,
// BRANCHLESS LIF FAST PATH: per t, compute all 8 m_j with no per-pixel
// branches (identical expressions -> identical bits), OR the spike
// predicates, ONE wave-uniform ballot; only if some pixel spiked run the
// exact original per-pixel WTA (starting from stored m_j). Removes 8
// ballot-reads + 16 branches per t in the ~99% no-spike case and lets the
// compiler interleave the 8 independent sigmoid chains (exp->div ~40cyc).
// Grid = B*H*2 = 4096 x 256; mem[8] in registers across all t.
// ---------------------------------------------------------------------------
__global__ __launch_bounds__(256) void fused_kernel(
    const float* __restrict__ x,              // (T,B,3,64,64)
    const float* __restrict__ Wt,             // (64,3,3,3)
    const unsigned int* __restrict__ thr_raw, // (T,64)
    float* __restrict__ out)                  // (T,B,64,64,64) pre-zeroed
{
    __shared__ f32x2 sx[5][CIN][3][36];       // 12,960 B, t-pair interleaved

    const int tid  = threadIdx.x;
    const int lane = tid & 63;                            // channel
    const int wave = tid >> 6;
    const int p0   = __builtin_amdgcn_readfirstlane(wave * 8);  // local px base
    const int b    = blockIdx.x >> 7;
    const int h    = (blockIdx.x >> 1) & 63;
    const int w0   = (blockIdx.x & 1) << 5;               // half-row start

    LOAD_WP

    // ---- stage all 5 t-pairs: rows h-1..h+1, cols w0-1..w0+32 ----
    {
        const float* xb0 = x + (size_t)b * (CIN * HW);
        const size_t ts = (size_t)BB * CIN * HW;
        for (int l = tid; l < 5 * 306; l += 256) {        // 306 = 3*3*34
            int tp  = l / 306;
            int r0  = l - tp * 306;
            int ci  = r0 / 102;
            int r1  = r0 - ci * 102;
            int r   = r1 / 34;
            int col = r1 - r * 34;
            int gh = h + r - 1;
            int gw = w0 + col - 1;
            f32x2 v; v.x = 0.f; v.y = 0.f;
            if (gh >= 0 && gh < HH && gw >= 0 && gw < WW) {
                size_t off = (size_t)ci * HW + gh * WW + gw;
                v.x = xb0[(size_t)(2 * tp)     * ts + off];
                v.y = xb0[(size_t)(2 * tp + 1) * ts + off];
            }
            sx[tp][ci][r][col] = v;
        }
    }

    float mem[8];
    #pragma unroll
    for (int j = 0; j < 8; j++) mem[j] = 0.f;

    __syncthreads();   // the only barrier in this kernel

// fast part: compute m (bit-identical expressions), accumulate spike-or
#define LIF_M(J, V) {                                                      \
        float cur = fmaxf(V, 0.f);                                         \
        float z   = (cur - s04) * sinv;                                    \
        float sig = 1.0f / (1.0f + expf(-z));                              \
        mv[J] = mem[J] * DECAY + thr * sig;                                \
        spor |= (mv[J] > thr) ? 1 : 0;                                     \
    }
// slow part: exact original per-pixel WTA, starting from stored m
#define LIF_W(J) {                                                         \
        float m   = mv[J];                                                 \
        int   sp  = m > thr;                                               \
        float score = sp ? m : 0.f;                                        \
        unsigned long long blt = __ballot(sp);                             \
        int fr = 0, sp_any = 0;                                            \
        if (blt) {                                                         \
            float bs = score;                                              \
            int   bc = lane;                                               \
            _Pragma("unroll")                                              \
            for (int off = 32; off > 0; off >>= 1) {                       \
                float so = __shfl_xor(bs, off, 64);                        \
                int   co = __shfl_xor(bc, off, 64);                        \
                if (so > bs || (so == bs && co < bc)) { bs = so; bc = co; }\
            }                                                              \
            int spw = __shfl(sp, bc, 64);   /* winner's spike = any_sp */  \
            fr     = (lane == bc) && sp;                                   \
            sp_any = spw;                                                  \
        }                                                                  \
        mem[J] = fr ? 0.f : (m - (sp_any ? sinh_ : 0.f));                  \
        if (fr) fmask |= (1 << (J));                                       \
    }

#define LIF_T(TIDX, F)                                                     \
    {                                                                      \
        float thr   = dec_f(F) + 1e-4f;                                    \
        float sinv  = 8.0f / thr;                                          \
        float s04   = 0.4f * thr;                                          \
        float sinh_ = INH * thr;                                           \
        int spor = 0;                                                      \
        float mv[8];                                                       \
        LIF_M(0, a0.SEL); LIF_M(1, a1.SEL); LIF_M(2, a2.SEL); LIF_M(3, a3.SEL); \
        LIF_M(4, a4.SEL); LIF_M(5, a5.SEL); LIF_M(6, a6.SEL); LIF_M(7, a7.SEL); \
        if (__ballot(spor)) {   /* rare: some pixel spiked in this wave */ \
            int fmask = 0;                                                 \
            LIF_W(0); LIF_W(1); LIF_W(2); LIF_W(3);                        \
            LIF_W(4); LIF_W(5); LIF_W(6); LIF_W(7);                        \
            if (fmask) {                                                   \
                float* os = out + (((size_t)(TIDX) * BB + b) * COUT) * HW  \
                          + h * WW + w0;                                   \
                _Pragma("unroll")                                          \
                for (int j = 0; j < 8; j++)                                \
                    if (fmask & (1 << j))                                  \
                        os[(size_t)lane * HW + p0 + j] = 1.0f;             \
            }                                                              \
        } else {                                                           \
            _Pragma("unroll")                                              \
            for (int j = 0; j < 8; j++) mem[j] = mv[j];                    \
        }                                                                  \
    }

    #pragma unroll 1
    for (int tp = 0; tp < 5; tp++) {
        // both thresholds loaded early (latency hides under conv)
        unsigned int tru0 = thr_raw[(2 * tp)     * COUT + lane];
        unsigned int tru1 = thr_raw[(2 * tp + 1) * COUT + lane];

        f32x2 a0={0.f,0.f},a1={0.f,0.f},a2={0.f,0.f},a3={0.f,0.f},
              a4={0.f,0.f},a5={0.f,0.f},a6={0.f,0.f},a7={0.f,0.f};
        #pragma unroll
        for (int ci = 0; ci < CIN; ci++)
            #pragma unroll
            for (int kh = 0; kh < 3; kh++)
                CKH(&sx[tp][ci][kh][p0], ci * 9 + kh * 3);

#define SEL x
        LIF_T(2 * tp, tru0)
#undef SEL
#define SEL y
        LIF_T(2 * tp + 1, tru1)
#undef SEL
    }
#undef LIF_T
#undef LIF_W
#undef LIF_M
}

// ---------------------------------------------------------------------------
extern "C" void kernel_launch(void* const* d_in, const int* in_sizes, int n_in,
                              void* d_out, int out_size, void* d_ws, size_t ws_size,
                              hipStream_t stream) {
    const float* x = (const float*)d_in[0];   // (T,B,3,64,64)
    const float* W = (const float*)d_in[1];   // (64,3,3,3)
    float* out     = (float*)d_out;           // (T,B,64,64,64)

    unsigned int* thr = (unsigned int*)d_ws;  // (T,64) — only 2.5 KB of ws used
    hipMemsetAsync(thr, 0, TT * COUT * sizeof(unsigned int), stream);

    thr_kernel<<<dim3(HH / 4, BB, TT / 2), 256, 0, stream>>>(x, W, thr, out);
    fused_kernel<<<dim3(BB * HH * 2), 256, 0, stream>>>(x, W, thr, out);
}